// Round 1
// baseline (5282.061 us; speedup 1.0000x reference)
//
#include <hip/hip_runtime.h>

#define N_NODES 50000
#define N_EDGES 200000
#define N_TRAIN 100000
#define DIM     512
#define NCLS    7

// ---------------- small utility kernels ----------------

__global__ void zero_kernel(float* p, int n) {
    int i = blockIdx.x * blockDim.x + threadIdx.x;
    if (i < n) p[i] = 0.0f;
}

// dst = src * (1 + *eps)   (eps == nullptr -> plain copy)
__global__ void scalecopy_kernel(const float* __restrict__ src, float* __restrict__ dst,
                                 const float* eps_or_null, size_t n4) {
    float s = 1.0f;
    if (eps_or_null) s = 1.0f + *eps_or_null;
    size_t i = (size_t)blockIdx.x * blockDim.x + threadIdx.x;
    size_t stride = (size_t)gridDim.x * blockDim.x;
    const float4* s4 = (const float4*)src;
    float4* d4 = (float4*)dst;
    for (; i < n4; i += stride) {
        float4 v = s4[i];
        v.x *= s; v.y *= s; v.z *= s; v.w *= s;
        d4[i] = v;
    }
}

// dst_feat[dst[e]] += src_feat[src[e]]  (one block per edge, 128 thr = 128 float4)
__global__ __launch_bounds__(128) void scatter_kernel(const float* __restrict__ src_feat,
                                                      float* __restrict__ dst_feat,
                                                      const int* __restrict__ ei) {
    int e = blockIdx.x;
    int s = ei[e];
    int d = ei[N_EDGES + e];
    const float4* sp = (const float4*)(src_feat + (size_t)s * DIM);
    float* dp = dst_feat + (size_t)d * DIM;
    float4 v = sp[threadIdx.x];
    int c = threadIdx.x * 4;
    atomicAdd(dp + c + 0, v.x);
    atomicAdd(dp + c + 1, v.y);
    atomicAdd(dp + c + 2, v.z);
    atomicAdd(dp + c + 3, v.w);
}

// ---------------- fp32 GEMM: C = A(Mx512) @ W(512x512) [+bias][+addmat][relu] ----------------

#define BM 128
#define BN 128
#define BK 16

__global__ __launch_bounds__(256) void gemm_kernel(
    const float* __restrict__ A, const float* __restrict__ W,
    const float* __restrict__ bias,     // 512 or nullptr
    const float* __restrict__ addmat,   // Mx512 or nullptr
    float* __restrict__ Cm, int M, int relu)
{
    __shared__ __align__(16) float As[BK][BM];   // transposed: As[k][m]
    __shared__ __align__(16) float Ws[BK][BN];

    int tid = threadIdx.x;
    int bm = blockIdx.x * BM;
    int bn = blockIdx.y * BN;
    int tm = (tid >> 4) * 8;   // 0..120
    int tn = (tid & 15) * 8;   // 0..120

    float acc[8][8];
#pragma unroll
    for (int i = 0; i < 8; i++)
#pragma unroll
        for (int j = 0; j < 8; j++) acc[i][j] = 0.0f;

    for (int k0 = 0; k0 < DIM; k0 += BK) {
#pragma unroll
        for (int l = 0; l < 2; l++) {
            int f = tid + l * 256;
            // A tile: 128 rows x 16 cols = 512 float4
            int ar = f >> 2;
            int ac4 = (f & 3) * 4;
            float4 v = make_float4(0.f, 0.f, 0.f, 0.f);
            int grow = bm + ar;
            if (grow < M) v = *(const float4*)(A + (size_t)grow * DIM + k0 + ac4);
            As[ac4 + 0][ar] = v.x;
            As[ac4 + 1][ar] = v.y;
            As[ac4 + 2][ar] = v.z;
            As[ac4 + 3][ar] = v.w;
            // W tile: 16 rows x 128 cols = 512 float4
            int wr = f >> 5;
            int wc4 = (f & 31) * 4;
            float4 wv = *(const float4*)(W + (size_t)(k0 + wr) * DIM + bn + wc4);
            *(float4*)&Ws[wr][wc4] = wv;
        }
        __syncthreads();
#pragma unroll
        for (int kk = 0; kk < BK; kk++) {
            float a[8], b[8];
            *(float4*)&a[0] = *(const float4*)&As[kk][tm];
            *(float4*)&a[4] = *(const float4*)&As[kk][tm + 4];
            *(float4*)&b[0] = *(const float4*)&Ws[kk][tn];
            *(float4*)&b[4] = *(const float4*)&Ws[kk][tn + 4];
#pragma unroll
            for (int i = 0; i < 8; i++)
#pragma unroll
                for (int j = 0; j < 8; j++)
                    acc[i][j] += a[i] * b[j];
        }
        __syncthreads();
    }

    // epilogue
#pragma unroll
    for (int i = 0; i < 8; i++) {
        int grow = bm + tm + i;
        if (grow >= M) break;
#pragma unroll
        for (int j4 = 0; j4 < 8; j4 += 4) {
            int gcol = bn + tn + j4;
            float4 r;
            r.x = acc[i][j4 + 0];
            r.y = acc[i][j4 + 1];
            r.z = acc[i][j4 + 2];
            r.w = acc[i][j4 + 3];
            if (bias) {
                r.x += bias[gcol + 0]; r.y += bias[gcol + 1];
                r.z += bias[gcol + 2]; r.w += bias[gcol + 3];
            }
            if (addmat) {
                float4 m = *(const float4*)(addmat + (size_t)grow * DIM + gcol);
                r.x += m.x; r.y += m.y; r.z += m.z; r.w += m.w;
            }
            if (relu) {
                r.x = fmaxf(r.x, 0.f); r.y = fmaxf(r.y, 0.f);
                r.z = fmaxf(r.z, 0.f); r.w = fmaxf(r.w, 0.f);
            }
            *(float4*)(Cm + (size_t)grow * DIM + gcol) = r;
        }
    }
}

// ---------------- batch norm ----------------

// partial column sums/sumsq into st[0..511], st[512..1023]
__global__ __launch_bounds__(256) void bn_stats_kernel(const float* __restrict__ X,
                                                       float* __restrict__ st, int M) {
    int t = threadIdx.x;
    int rows_per_block = (M + gridDim.x - 1) / gridDim.x;
    int r0 = blockIdx.x * rows_per_block;
    int r1 = min(M, r0 + rows_per_block);
    float s0 = 0.f, q0 = 0.f, s1 = 0.f, q1 = 0.f;
    for (int r = r0; r < r1; ++r) {
        const float* row = X + (size_t)r * DIM;
        float a = row[t];
        float b = row[t + 256];
        s0 += a; q0 += a * a;
        s1 += b; q1 += b * b;
    }
    atomicAdd(&st[t], s0);
    atomicAdd(&st[DIM + t], q0);
    atomicAdd(&st[t + 256], s1);
    atomicAdd(&st[DIM + t + 256], q1);
}

// st[1024..1535] = scale, st[1536..2047] = shift
__global__ void bn_finalize_kernel(float* st, const float* __restrict__ g,
                                   const float* __restrict__ b, int M) {
    int c = threadIdx.x;  // 512 threads
    float mean = st[c] / (float)M;
    float var = st[DIM + c] / (float)M - mean * mean;
    float sc = g[c] * rsqrtf(var + 1e-5f);
    st[1024 + c] = sc;
    st[1536 + c] = b[c] - mean * sc;
}

__global__ void bn_apply_kernel(float* __restrict__ X, const float* __restrict__ st,
                                int M, int relu) {
    const float* scale = st + 1024;
    const float* shift = st + 1536;
    size_t n4 = (size_t)M * DIM / 4;
    size_t i = (size_t)blockIdx.x * blockDim.x + threadIdx.x;
    size_t stride = (size_t)gridDim.x * blockDim.x;
    float4* X4 = (float4*)X;
    for (; i < n4; i += stride) {
        int col4 = (int)(i & (DIM / 4 - 1)) * 4;
        float4 v = X4[i];
        v.x = v.x * scale[col4 + 0] + shift[col4 + 0];
        v.y = v.y * scale[col4 + 1] + shift[col4 + 1];
        v.z = v.z * scale[col4 + 2] + shift[col4 + 2];
        v.w = v.w * scale[col4 + 3] + shift[col4 + 3];
        if (relu) {
            v.x = fmaxf(v.x, 0.f); v.y = fmaxf(v.y, 0.f);
            v.z = fmaxf(v.z, 0.f); v.w = fmaxf(v.w, 0.f);
        }
        X4[i] = v;
    }
}

// ---------------- final pair gather + (T,512)@(512,7) ----------------

__global__ __launch_bounds__(256) void pair_kernel(const float* __restrict__ H,
                                                   const int* __restrict__ ei,
                                                   const int* __restrict__ teid,
                                                   const float* __restrict__ W,  // 512x7
                                                   const float* __restrict__ bias,
                                                   float* __restrict__ out) {
    __shared__ float Wl[DIM * NCLS];
    for (int i = threadIdx.x; i < DIM * NCLS; i += 256) Wl[i] = W[i];
    __syncthreads();

    int wave = threadIdx.x >> 6;
    int lane = threadIdx.x & 63;
    int t = blockIdx.x * 4 + wave;
    if (t >= N_TRAIN) return;
    int id = teid[t];
    int n0 = ei[id];
    int n1 = ei[N_EDGES + id];
    const float4* a4 = (const float4*)(H + (size_t)n0 * DIM);
    const float4* b4 = (const float4*)(H + (size_t)n1 * DIM);
    float4 a0 = a4[lane * 2], a1 = a4[lane * 2 + 1];
    float4 b0 = b4[lane * 2], b1 = b4[lane * 2 + 1];
    float p[8] = {a0.x * b0.x, a0.y * b0.y, a0.z * b0.z, a0.w * b0.w,
                  a1.x * b1.x, a1.y * b1.y, a1.z * b1.z, a1.w * b1.w};
    int d0 = lane * 8;
    float acc[NCLS];
#pragma unroll
    for (int c = 0; c < NCLS; c++) acc[c] = 0.f;
#pragma unroll
    for (int q = 0; q < 8; q++) {
        const float* wrow = &Wl[(d0 + q) * NCLS];
#pragma unroll
        for (int c = 0; c < NCLS; c++) acc[c] += p[q] * wrow[c];
    }
#pragma unroll
    for (int off = 32; off; off >>= 1)
#pragma unroll
        for (int c = 0; c < NCLS; c++) acc[c] += __shfl_down(acc[c], off);
    if (lane == 0) {
#pragma unroll
        for (int c = 0; c < NCLS; c++) out[(size_t)t * NCLS + c] = acc[c] + bias[c];
    }
}

// ---------------- launch ----------------

extern "C" void kernel_launch(void* const* d_in, const int* in_sizes, int n_in,
                              void* d_out, int out_size, void* d_ws, size_t ws_size,
                              hipStream_t stream) {
    const float* x      = (const float*)d_in[0];
    const float* graph  = (const float*)d_in[1];
    const int*   ei     = (const int*)d_in[2];
    const int*   teid   = (const int*)d_in[3];
    const float* W_sub  = (const float*)d_in[4];
    const float* bn1_g  = (const float*)d_in[5];
    const float* bn1_b  = (const float*)d_in[6];
    const float* fcx_W  = (const float*)d_in[7];
    const float* fcx_b  = (const float*)d_in[8];
    const float* eps1   = (const float*)d_in[9];
    const float* g_W1   = (const float*)d_in[10];
    const float* g_b1   = (const float*)d_in[11];
    const float* g_W2   = (const float*)d_in[12];
    const float* g_b2   = (const float*)d_in[13];
    const float* gbn_g  = (const float*)d_in[14];
    const float* gbn_b  = (const float*)d_in[15];
    const float* lin1_W = (const float*)d_in[16];
    const float* lin1_b = (const float*)d_in[17];
    const float* lin2_W = (const float*)d_in[18];
    const float* lin2_b = (const float*)d_in[19];
    const float* fc2_W  = (const float*)d_in[20];
    const float* fc2_b  = (const float*)d_in[21];
    float* out = (float*)d_out;

    char* ws = (char*)d_ws;
    size_t NB = (size_t)N_NODES * DIM * sizeof(float);
    float* Abuf = (float*)(ws);
    float* Bbuf = (float*)(ws + NB);
    float* Cbuf = (float*)(ws + 2 * NB);
    float* st1  = (float*)(ws + 3 * NB);
    float* st2  = st1 + 2048;

    size_t n4 = (size_t)N_NODES * DIM / 4;
    dim3 ggrid((N_NODES + BM - 1) / BM, DIM / BN);

    // zero both stat regions (4096 floats)
    zero_kernel<<<16, 256, 0, stream>>>(st1, 4096);

    // agg_s = graph + segment_sum(graph[src], dst)
    scalecopy_kernel<<<2048, 256, 0, stream>>>(graph, Abuf, nullptr, n4);
    scatter_kernel<<<N_EDGES, 128, 0, stream>>>(graph, Abuf, ei);

    // sub_x = agg_s @ W_sub + graph ;  BN+relu in-place
    gemm_kernel<<<ggrid, 256, 0, stream>>>(Abuf, W_sub, nullptr, graph, Bbuf, N_NODES, 0);
    bn_stats_kernel<<<256, 256, 0, stream>>>(Bbuf, st1, N_NODES);
    bn_finalize_kernel<<<1, 512, 0, stream>>>(st1, bn1_g, bn1_b, N_NODES);
    bn_apply_kernel<<<2048, 256, 0, stream>>>(Bbuf, st1, N_NODES, 1);

    // h = x @ fcx_W + fcx_b
    gemm_kernel<<<ggrid, 256, 0, stream>>>(x, fcx_W, fcx_b, nullptr, Abuf, N_NODES, 0);

    // agg = (1+eps1)*h + segment_sum(h[src], dst)
    scalecopy_kernel<<<2048, 256, 0, stream>>>(Abuf, Cbuf, eps1, n4);
    scatter_kernel<<<N_EDGES, 128, 0, stream>>>(Abuf, Cbuf, ei);

    // h = relu(agg @ g_W1 + g_b1) ; h = relu(h @ g_W2 + g_b2)
    gemm_kernel<<<ggrid, 256, 0, stream>>>(Cbuf, g_W1, g_b1, nullptr, Abuf, N_NODES, 1);
    gemm_kernel<<<ggrid, 256, 0, stream>>>(Abuf, g_W2, g_b2, nullptr, Cbuf, N_NODES, 1);

    // h = BN(h) (no relu)
    bn_stats_kernel<<<256, 256, 0, stream>>>(Cbuf, st2, N_NODES);
    bn_finalize_kernel<<<1, 512, 0, stream>>>(st2, gbn_g, gbn_b, N_NODES);
    bn_apply_kernel<<<2048, 256, 0, stream>>>(Cbuf, st2, N_NODES, 0);

    // h = relu(h @ lin1_W + lin1_b) ; h = h @ lin2_W + lin2_b + sub_x
    gemm_kernel<<<ggrid, 256, 0, stream>>>(Cbuf, lin1_W, lin1_b, nullptr, Abuf, N_NODES, 1);
    gemm_kernel<<<ggrid, 256, 0, stream>>>(Abuf, lin2_W, lin2_b, Bbuf, Cbuf, N_NODES, 0);

    // out = (h[n0] * h[n1]) @ fc2_W + fc2_b
    pair_kernel<<<(N_TRAIN + 3) / 4, 256, 0, stream>>>(Cbuf, ei, teid, fc2_W, fc2_b, out);
}

// Round 2
// 2756.111 us; speedup vs baseline: 1.9165x; 1.9165x over previous
//
#include <hip/hip_runtime.h>

#define N_NODES 50000
#define N_EDGES 200000
#define N_TRAIN 100000
#define DIM     512
#define NCLS    7
#define NSB     ((N_NODES + 255) / 256)   // scan blocks = 196

// ---------------- small utility kernels ----------------

__global__ void zero_kernel(float* p, int n) {
    int i = blockIdx.x * blockDim.x + threadIdx.x;
    if (i < n) p[i] = 0.0f;
}

// ---------------- CSR build (by dst) ----------------

__global__ void hist_kernel(const int* __restrict__ ei, int* __restrict__ cnt) {
    int e = blockIdx.x * blockDim.x + threadIdx.x;
    if (e < N_EDGES) atomicAdd(&cnt[ei[N_EDGES + e]], 1);
}

__global__ __launch_bounds__(256) void scan1_kernel(const int* __restrict__ cnt,
                                                    int* __restrict__ off,
                                                    int* __restrict__ bsum) {
    __shared__ int s[256];
    int t = threadIdx.x, b = blockIdx.x;
    int i = b * 256 + t;
    s[t] = (i < N_NODES) ? cnt[i] : 0;
    __syncthreads();
    for (int d = 1; d < 256; d <<= 1) {
        int add = (t >= d) ? s[t - d] : 0;
        __syncthreads();
        s[t] += add;
        __syncthreads();
    }
    if (i < N_NODES) off[i + 1] = s[t];
    if (t == 255) bsum[b] = s[255];
}

__global__ __launch_bounds__(256) void scan2_kernel(int* bsum) {
    __shared__ int s[256];
    int t = threadIdx.x;
    s[t] = (t < NSB) ? bsum[t] : 0;
    __syncthreads();
    for (int d = 1; d < 256; d <<= 1) {
        int add = (t >= d) ? s[t - d] : 0;
        __syncthreads();
        s[t] += add;
        __syncthreads();
    }
    if (t < NSB) bsum[t] = s[t];
}

__global__ __launch_bounds__(256) void scan3_kernel(int* off, const int* __restrict__ bsum,
                                                    int* __restrict__ wcur) {
    int t = threadIdx.x, b = blockIdx.x;
    int i = b * 256 + t;
    if (i == 0) off[0] = 0;
    if (i < N_NODES) {
        int v = off[i + 1] + (b > 0 ? bsum[b - 1] : 0);
        off[i + 1] = v;
    }
}

__global__ void fillprep_kernel(const int* __restrict__ off, int* __restrict__ wcur) {
    int i = blockIdx.x * blockDim.x + threadIdx.x;
    if (i < N_NODES) wcur[i] = off[i];
}

__global__ void fill_kernel(const int* __restrict__ ei, int* __restrict__ wcur,
                            int* __restrict__ srclist) {
    int e = blockIdx.x * blockDim.x + threadIdx.x;
    if (e < N_EDGES) {
        int d = ei[N_EDGES + e];
        int pos = atomicAdd(&wcur[d], 1);
        srclist[pos] = ei[e];
    }
}

// ---------------- aggregation: out[n] = scale*base[n] + sum_{e in csr[n]} feat[src[e]] ----

__global__ __launch_bounds__(128) void gather_kernel(const float* __restrict__ feat,
                                                     const float* __restrict__ base,
                                                     const float* eps_or_null,
                                                     const int* __restrict__ off,
                                                     const int* __restrict__ srclist,
                                                     float* __restrict__ outf) {
    int n = blockIdx.x;
    int t = threadIdx.x;
    float s = 1.0f;
    if (eps_or_null) s = 1.0f + *eps_or_null;
    int e0 = off[n], e1 = off[n + 1];
    float4 acc = ((const float4*)(base + (size_t)n * DIM))[t];
    acc.x *= s; acc.y *= s; acc.z *= s; acc.w *= s;
    for (int e = e0; e < e1; ++e) {
        int srcn = srclist[e];
        float4 v = ((const float4*)(feat + (size_t)srcn * DIM))[t];
        acc.x += v.x; acc.y += v.y; acc.z += v.z; acc.w += v.w;
    }
    ((float4*)(outf + (size_t)n * DIM))[t] = acc;
}

// ---------------- fp32 GEMM: C = A(Mx512) @ W(512x512) [+bias][+addmat][relu] ----------------

#define BM 128
#define BN 128
#define BK 16

__global__ __launch_bounds__(256) void gemm_kernel(
    const float* __restrict__ A, const float* __restrict__ W,
    const float* __restrict__ bias,     // 512 or nullptr
    const float* __restrict__ addmat,   // Mx512 or nullptr
    float* __restrict__ Cm, int M, int relu)
{
    __shared__ __align__(16) float As[BK][BM];   // transposed: As[k][m]
    __shared__ __align__(16) float Ws[BK][BN];

    int tid = threadIdx.x;
    int bm = blockIdx.x * BM;
    int bn = blockIdx.y * BN;
    int tm = (tid >> 4) * 8;   // 0..120
    int tn = (tid & 15) * 8;   // 0..120

    float acc[8][8];
#pragma unroll
    for (int i = 0; i < 8; i++)
#pragma unroll
        for (int j = 0; j < 8; j++) acc[i][j] = 0.0f;

    for (int k0 = 0; k0 < DIM; k0 += BK) {
#pragma unroll
        for (int l = 0; l < 2; l++) {
            int f = tid + l * 256;
            // A tile: 128 rows x 16 cols = 512 float4
            int ar = f >> 2;
            int ac4 = (f & 3) * 4;
            float4 v = make_float4(0.f, 0.f, 0.f, 0.f);
            int grow = bm + ar;
            if (grow < M) v = *(const float4*)(A + (size_t)grow * DIM + k0 + ac4);
            As[ac4 + 0][ar] = v.x;
            As[ac4 + 1][ar] = v.y;
            As[ac4 + 2][ar] = v.z;
            As[ac4 + 3][ar] = v.w;
            // W tile: 16 rows x 128 cols = 512 float4
            int wr = f >> 5;
            int wc4 = (f & 31) * 4;
            float4 wv = *(const float4*)(W + (size_t)(k0 + wr) * DIM + bn + wc4);
            *(float4*)&Ws[wr][wc4] = wv;
        }
        __syncthreads();
#pragma unroll
        for (int kk = 0; kk < BK; kk++) {
            float a[8], b[8];
            *(float4*)&a[0] = *(const float4*)&As[kk][tm];
            *(float4*)&a[4] = *(const float4*)&As[kk][tm + 4];
            *(float4*)&b[0] = *(const float4*)&Ws[kk][tn];
            *(float4*)&b[4] = *(const float4*)&Ws[kk][tn + 4];
#pragma unroll
            for (int i = 0; i < 8; i++)
#pragma unroll
                for (int j = 0; j < 8; j++)
                    acc[i][j] += a[i] * b[j];
        }
        __syncthreads();
    }

    // epilogue
#pragma unroll
    for (int i = 0; i < 8; i++) {
        int grow = bm + tm + i;
        if (grow >= M) break;
#pragma unroll
        for (int j4 = 0; j4 < 8; j4 += 4) {
            int gcol = bn + tn + j4;
            float4 r;
            r.x = acc[i][j4 + 0];
            r.y = acc[i][j4 + 1];
            r.z = acc[i][j4 + 2];
            r.w = acc[i][j4 + 3];
            if (bias) {
                r.x += bias[gcol + 0]; r.y += bias[gcol + 1];
                r.z += bias[gcol + 2]; r.w += bias[gcol + 3];
            }
            if (addmat) {
                float4 m = *(const float4*)(addmat + (size_t)grow * DIM + gcol);
                r.x += m.x; r.y += m.y; r.z += m.z; r.w += m.w;
            }
            if (relu) {
                r.x = fmaxf(r.x, 0.f); r.y = fmaxf(r.y, 0.f);
                r.z = fmaxf(r.z, 0.f); r.w = fmaxf(r.w, 0.f);
            }
            *(float4*)(Cm + (size_t)grow * DIM + gcol) = r;
        }
    }
}

// ---------------- batch norm ----------------

__global__ __launch_bounds__(256) void bn_stats_kernel(const float* __restrict__ X,
                                                       float* __restrict__ st, int M) {
    int t = threadIdx.x;
    int rows_per_block = (M + gridDim.x - 1) / gridDim.x;
    int r0 = blockIdx.x * rows_per_block;
    int r1 = min(M, r0 + rows_per_block);
    float s0 = 0.f, q0 = 0.f, s1 = 0.f, q1 = 0.f;
    for (int r = r0; r < r1; ++r) {
        const float* row = X + (size_t)r * DIM;
        float a = row[t];
        float b = row[t + 256];
        s0 += a; q0 += a * a;
        s1 += b; q1 += b * b;
    }
    atomicAdd(&st[t], s0);
    atomicAdd(&st[DIM + t], q0);
    atomicAdd(&st[t + 256], s1);
    atomicAdd(&st[DIM + t + 256], q1);
}

__global__ void bn_finalize_kernel(float* st, const float* __restrict__ g,
                                   const float* __restrict__ b, int M) {
    int c = threadIdx.x;  // 512 threads
    float mean = st[c] / (float)M;
    float var = st[DIM + c] / (float)M - mean * mean;
    float sc = g[c] * rsqrtf(var + 1e-5f);
    st[1024 + c] = sc;
    st[1536 + c] = b[c] - mean * sc;
}

__global__ void bn_apply_kernel(float* __restrict__ X, const float* __restrict__ st,
                                int M, int relu) {
    const float* scale = st + 1024;
    const float* shift = st + 1536;
    size_t n4 = (size_t)M * DIM / 4;
    size_t i = (size_t)blockIdx.x * blockDim.x + threadIdx.x;
    size_t stride = (size_t)gridDim.x * blockDim.x;
    float4* X4 = (float4*)X;
    for (; i < n4; i += stride) {
        int col4 = (int)(i & (DIM / 4 - 1)) * 4;
        float4 v = X4[i];
        v.x = v.x * scale[col4 + 0] + shift[col4 + 0];
        v.y = v.y * scale[col4 + 1] + shift[col4 + 1];
        v.z = v.z * scale[col4 + 2] + shift[col4 + 2];
        v.w = v.w * scale[col4 + 3] + shift[col4 + 3];
        if (relu) {
            v.x = fmaxf(v.x, 0.f); v.y = fmaxf(v.y, 0.f);
            v.z = fmaxf(v.z, 0.f); v.w = fmaxf(v.w, 0.f);
        }
        X4[i] = v;
    }
}

// ---------------- final pair gather + (T,512)@(512,7) ----------------

__global__ __launch_bounds__(256) void pair_kernel(const float* __restrict__ H,
                                                   const int* __restrict__ ei,
                                                   const int* __restrict__ teid,
                                                   const float* __restrict__ W,  // 512x7
                                                   const float* __restrict__ bias,
                                                   float* __restrict__ out) {
    __shared__ float Wl[DIM * NCLS];
    for (int i = threadIdx.x; i < DIM * NCLS; i += 256) Wl[i] = W[i];
    __syncthreads();

    int wave = threadIdx.x >> 6;
    int lane = threadIdx.x & 63;
    int t = blockIdx.x * 4 + wave;
    if (t >= N_TRAIN) return;
    int id = teid[t];
    int n0 = ei[id];
    int n1 = ei[N_EDGES + id];
    const float4* a4 = (const float4*)(H + (size_t)n0 * DIM);
    const float4* b4 = (const float4*)(H + (size_t)n1 * DIM);
    float4 a0 = a4[lane * 2], a1 = a4[lane * 2 + 1];
    float4 b0 = b4[lane * 2], b1 = b4[lane * 2 + 1];
    float p[8] = {a0.x * b0.x, a0.y * b0.y, a0.z * b0.z, a0.w * b0.w,
                  a1.x * b1.x, a1.y * b1.y, a1.z * b1.z, a1.w * b1.w};
    int d0 = lane * 8;
    float acc[NCLS];
#pragma unroll
    for (int c = 0; c < NCLS; c++) acc[c] = 0.f;
#pragma unroll
    for (int q = 0; q < 8; q++) {
        const float* wrow = &Wl[(d0 + q) * NCLS];
#pragma unroll
        for (int c = 0; c < NCLS; c++) acc[c] += p[q] * wrow[c];
    }
#pragma unroll
    for (int off = 32; off; off >>= 1)
#pragma unroll
        for (int c = 0; c < NCLS; c++) acc[c] += __shfl_down(acc[c], off);
    if (lane == 0) {
#pragma unroll
        for (int c = 0; c < NCLS; c++) out[(size_t)t * NCLS + c] = acc[c] + bias[c];
    }
}

// ---------------- launch ----------------

extern "C" void kernel_launch(void* const* d_in, const int* in_sizes, int n_in,
                              void* d_out, int out_size, void* d_ws, size_t ws_size,
                              hipStream_t stream) {
    const float* x      = (const float*)d_in[0];
    const float* graph  = (const float*)d_in[1];
    const int*   ei     = (const int*)d_in[2];
    const int*   teid   = (const int*)d_in[3];
    const float* W_sub  = (const float*)d_in[4];
    const float* bn1_g  = (const float*)d_in[5];
    const float* bn1_b  = (const float*)d_in[6];
    const float* fcx_W  = (const float*)d_in[7];
    const float* fcx_b  = (const float*)d_in[8];
    const float* eps1   = (const float*)d_in[9];
    const float* g_W1   = (const float*)d_in[10];
    const float* g_b1   = (const float*)d_in[11];
    const float* g_W2   = (const float*)d_in[12];
    const float* g_b2   = (const float*)d_in[13];
    const float* gbn_g  = (const float*)d_in[14];
    const float* gbn_b  = (const float*)d_in[15];
    const float* lin1_W = (const float*)d_in[16];
    const float* lin1_b = (const float*)d_in[17];
    const float* lin2_W = (const float*)d_in[18];
    const float* lin2_b = (const float*)d_in[19];
    const float* fc2_W  = (const float*)d_in[20];
    const float* fc2_b  = (const float*)d_in[21];
    float* out = (float*)d_out;

    char* ws = (char*)d_ws;
    size_t NB = (size_t)N_NODES * DIM * sizeof(float);
    float* Abuf = (float*)(ws);
    float* Bbuf = (float*)(ws + NB);
    float* Cbuf = (float*)(ws + 2 * NB);
    float* st1  = (float*)(ws + 3 * NB);
    float* st2  = st1 + 2048;
    int* off     = (int*)(st2 + 2048);          // 50001 ints
    int* wcur    = off + (N_NODES + 1);         // 50000 ints (also counts)
    int* srclist = wcur + N_NODES;              // 200000 ints
    int* bsum    = srclist + N_EDGES;           // 256 ints

    dim3 ggrid((N_NODES + BM - 1) / BM, DIM / BN);

    // zero stats (4096 floats) + counts
    zero_kernel<<<16, 256, 0, stream>>>(st1, 4096);
    zero_kernel<<<NSB, 256, 0, stream>>>((float*)wcur, N_NODES);

    // build CSR by dst
    hist_kernel<<<(N_EDGES + 255) / 256, 256, 0, stream>>>(ei, wcur);
    scan1_kernel<<<NSB, 256, 0, stream>>>(wcur, off, bsum);
    scan2_kernel<<<1, 256, 0, stream>>>(bsum);
    scan3_kernel<<<NSB, 256, 0, stream>>>(off, bsum, wcur);
    fillprep_kernel<<<NSB, 256, 0, stream>>>(off, wcur);
    fill_kernel<<<(N_EDGES + 255) / 256, 256, 0, stream>>>(ei, wcur, srclist);

    // agg_s = graph + segment_sum(graph[src], dst)
    gather_kernel<<<N_NODES, 128, 0, stream>>>(graph, graph, nullptr, off, srclist, Abuf);

    // sub_x = agg_s @ W_sub + graph ;  BN+relu in-place
    gemm_kernel<<<ggrid, 256, 0, stream>>>(Abuf, W_sub, nullptr, graph, Bbuf, N_NODES, 0);
    bn_stats_kernel<<<256, 256, 0, stream>>>(Bbuf, st1, N_NODES);
    bn_finalize_kernel<<<1, 512, 0, stream>>>(st1, bn1_g, bn1_b, N_NODES);
    bn_apply_kernel<<<2048, 256, 0, stream>>>(Bbuf, st1, N_NODES, 1);

    // h = x @ fcx_W + fcx_b
    gemm_kernel<<<ggrid, 256, 0, stream>>>(x, fcx_W, fcx_b, nullptr, Abuf, N_NODES, 0);

    // agg = (1+eps1)*h + segment_sum(h[src], dst)
    gather_kernel<<<N_NODES, 128, 0, stream>>>(Abuf, Abuf, eps1, off, srclist, Cbuf);

    // h = relu(agg @ g_W1 + g_b1) ; h = relu(h @ g_W2 + g_b2)
    gemm_kernel<<<ggrid, 256, 0, stream>>>(Cbuf, g_W1, g_b1, nullptr, Abuf, N_NODES, 1);
    gemm_kernel<<<ggrid, 256, 0, stream>>>(Abuf, g_W2, g_b2, nullptr, Cbuf, N_NODES, 1);

    // h = BN(h) (no relu)
    bn_stats_kernel<<<256, 256, 0, stream>>>(Cbuf, st2, N_NODES);
    bn_finalize_kernel<<<1, 512, 0, stream>>>(st2, gbn_g, gbn_b, N_NODES);
    bn_apply_kernel<<<2048, 256, 0, stream>>>(Cbuf, st2, N_NODES, 0);

    // h = relu(h @ lin1_W + lin1_b) ; h = h @ lin2_W + lin2_b + sub_x
    gemm_kernel<<<ggrid, 256, 0, stream>>>(Cbuf, lin1_W, lin1_b, nullptr, Abuf, N_NODES, 1);
    gemm_kernel<<<ggrid, 256, 0, stream>>>(Abuf, lin2_W, lin2_b, Bbuf, Cbuf, N_NODES, 0);

    // out = (h[n0] * h[n1]) @ fc2_W + fc2_b
    pair_kernel<<<(N_TRAIN + 3) / 4, 256, 0, stream>>>(Cbuf, ei, teid, fc2_W, fc2_b, out);
}

// Round 3
// 1747.990 us; speedup vs baseline: 3.0218x; 1.5767x over previous
//
#include <hip/hip_runtime.h>

#define N_NODES 50000
#define N_EDGES 200000
#define N_TRAIN 100000
#define DIM     512
#define NCLS    7
#define NSB     ((N_NODES + 255) / 256)   // scan blocks = 196

typedef unsigned short ushort;
typedef __bf16 bf16x8 __attribute__((ext_vector_type(8)));
typedef float  f32x4  __attribute__((ext_vector_type(4)));

// ---------- bf16 helpers ----------
__device__ __forceinline__ ushort f2bf_rne(float f) {
    union { float f; unsigned u; } v; v.f = f;
    unsigned u = v.u;
    unsigned r = (u + 0x7fffu + ((u >> 16) & 1u)) >> 16;
    return (ushort)r;
}
__device__ __forceinline__ float bf2f(ushort h) {
    union { unsigned u; float f; } v; v.u = ((unsigned)h) << 16; return v.f;
}
__device__ __forceinline__ void split_bf(float f, ushort& h, ushort& l) {
    h = f2bf_rne(f);
    l = f2bf_rne(f - bf2f(h));
}

__device__ __forceinline__ void gload_lds16(const void* g, void* l) {
    __builtin_amdgcn_global_load_lds((const __attribute__((address_space(1))) unsigned int*)g,
                                     (__attribute__((address_space(3))) unsigned int*)l,
                                     16, 0, 0);
}

// ---------------- small utility kernels ----------------

__global__ void zero_kernel(float* p, int n) {
    int i = blockIdx.x * blockDim.x + threadIdx.x;
    if (i < n) p[i] = 0.0f;
}

// ---------------- CSR build (by dst) ----------------

__global__ void hist_kernel(const int* __restrict__ ei, int* __restrict__ cnt) {
    int e = blockIdx.x * blockDim.x + threadIdx.x;
    if (e < N_EDGES) atomicAdd(&cnt[ei[N_EDGES + e]], 1);
}

__global__ __launch_bounds__(256) void scan1_kernel(const int* __restrict__ cnt,
                                                    int* __restrict__ off,
                                                    int* __restrict__ bsum) {
    __shared__ int s[256];
    int t = threadIdx.x, b = blockIdx.x;
    int i = b * 256 + t;
    s[t] = (i < N_NODES) ? cnt[i] : 0;
    __syncthreads();
    for (int d = 1; d < 256; d <<= 1) {
        int add = (t >= d) ? s[t - d] : 0;
        __syncthreads();
        s[t] += add;
        __syncthreads();
    }
    if (i < N_NODES) off[i + 1] = s[t];
    if (t == 255) bsum[b] = s[255];
}

__global__ __launch_bounds__(256) void scan2_kernel(int* bsum) {
    __shared__ int s[256];
    int t = threadIdx.x;
    s[t] = (t < NSB) ? bsum[t] : 0;
    __syncthreads();
    for (int d = 1; d < 256; d <<= 1) {
        int add = (t >= d) ? s[t - d] : 0;
        __syncthreads();
        s[t] += add;
        __syncthreads();
    }
    if (t < NSB) bsum[t] = s[t];
}

__global__ __launch_bounds__(256) void scan3_kernel(int* off, const int* __restrict__ bsum) {
    int t = threadIdx.x, b = blockIdx.x;
    int i = b * 256 + t;
    if (i == 0) off[0] = 0;
    if (i < N_NODES) off[i + 1] += (b > 0 ? bsum[b - 1] : 0);
}

__global__ void fillprep_kernel(const int* __restrict__ off, int* __restrict__ wcur) {
    int i = blockIdx.x * blockDim.x + threadIdx.x;
    if (i < N_NODES) wcur[i] = off[i];
}

__global__ void fill_kernel(const int* __restrict__ ei, int* __restrict__ wcur,
                            int* __restrict__ srclist) {
    int e = blockIdx.x * blockDim.x + threadIdx.x;
    if (e < N_EDGES) {
        int d = ei[N_EDGES + e];
        int pos = atomicAdd(&wcur[d], 1);
        srclist[pos] = ei[e];
    }
}

// ---- aggregation: out[n] = scale*base[n] + sum feat[src], emitted as bf16 hi/lo pair ----

__global__ __launch_bounds__(128) void gather_pair_kernel(const float* __restrict__ feat,
                                                          const float* __restrict__ base,
                                                          const float* eps_or_null,
                                                          const int* __restrict__ off,
                                                          const int* __restrict__ srclist,
                                                          ushort* __restrict__ oh,
                                                          ushort* __restrict__ ol) {
    int n = blockIdx.x;
    int t = threadIdx.x;
    float s = 1.0f;
    if (eps_or_null) s = 1.0f + *eps_or_null;
    int e0 = off[n], e1 = off[n + 1];
    float4 acc = ((const float4*)(base + (size_t)n * DIM))[t];
    acc.x *= s; acc.y *= s; acc.z *= s; acc.w *= s;
    for (int e = e0; e < e1; ++e) {
        int srcn = srclist[e];
        float4 v = ((const float4*)(feat + (size_t)srcn * DIM))[t];
        acc.x += v.x; acc.y += v.y; acc.z += v.z; acc.w += v.w;
    }
    size_t o = (size_t)n * DIM + t * 4;
    ushort h, l;
    split_bf(acc.x, h, l); oh[o + 0] = h; ol[o + 0] = l;
    split_bf(acc.y, h, l); oh[o + 1] = h; ol[o + 1] = l;
    split_bf(acc.z, h, l); oh[o + 2] = h; ol[o + 2] = l;
    split_bf(acc.w, h, l); oh[o + 3] = h; ol[o + 3] = l;
}

// ---- fp32 -> bf16 pair (for x) ----
__global__ void convert_pair_kernel(const float* __restrict__ X,
                                    ushort* __restrict__ oh, ushort* __restrict__ ol,
                                    size_t n4) {
    size_t i = (size_t)blockIdx.x * blockDim.x + threadIdx.x;
    size_t stride = (size_t)gridDim.x * blockDim.x;
    const float4* X4 = (const float4*)X;
    for (; i < n4; i += stride) {
        float4 v = X4[i];
        size_t o = i * 4;
        ushort h, l;
        split_bf(v.x, h, l); oh[o + 0] = h; ol[o + 0] = l;
        split_bf(v.y, h, l); oh[o + 1] = h; ol[o + 1] = l;
        split_bf(v.z, h, l); oh[o + 2] = h; ol[o + 2] = l;
        split_bf(v.w, h, l); oh[o + 3] = h; ol[o + 3] = l;
    }
}

// ---- W (K x N fp32) -> transposed bf16 hi/lo [N][K] ----
__global__ void wconvert_kernel(const float* __restrict__ W,
                                ushort* __restrict__ Th, ushort* __restrict__ Tl) {
    int idx = blockIdx.x * 256 + threadIdx.x;   // over 512*512
    int n = idx >> 9, k = idx & 511;
    float f = W[k * DIM + n];
    ushort h, l;
    split_bf(f, h, l);
    Th[idx] = h; Tl[idx] = l;
}

// ---------------- MFMA GEMM ----------------
// C(MxDIM) = (Ah+Al)(M x DIM) @ (Wh+Wl)(DIM x DIM), W given transposed [n][k].
// 3 products: Ah*Wh + Ah*Wl + Al*Wh. Tile 128x128, BK=32, 4 waves (2x2).
// Epilogue: +bias, +addmat, relu, out fp32 OR bf16 pair; optional fused column stats.

__global__ __launch_bounds__(256) void mfma_gemm_kernel(
    const ushort* __restrict__ Ah, const ushort* __restrict__ Al,
    const ushort* __restrict__ Bh, const ushort* __restrict__ Bl,   // W^T hi/lo [DIM][DIM]
    const float* __restrict__ bias,     // or null
    const float* __restrict__ addmat,   // or null
    float* __restrict__ Cf,             // mode 0 out
    ushort* __restrict__ Oh, ushort* __restrict__ Ol,  // mode 1 out
    float* __restrict__ stats,          // or null: [0..511] sum, [512..1023] sumsq
    int M, int relu, int mode)
{
    __shared__ __align__(16) ushort smem[4 * 128 * 32];   // Ah|Al|Bh|Bl tiles, 32KB

    int tid = threadIdx.x;
    int w = tid >> 6;       // wave 0..3
    int l = tid & 63;
    int wm = w >> 1, wn = w & 1;
    int bm = blockIdx.x * 128;
    int bn = blockIdx.y * 128;

    // wave-uniform staging source select
    const ushort* sbase;
    int rbase;
    if (w == 0)      { sbase = Ah; rbase = bm; }
    else if (w == 1) { sbase = Al; rbase = bm; }
    else if (w == 2) { sbase = Bh; rbase = bn; }
    else             { sbase = Bl; rbase = bn; }
    ushort* ldst = smem + w * 4096;

    f32x4 acc[4][4];
#pragma unroll
    for (int i = 0; i < 4; i++)
#pragma unroll
        for (int j = 0; j < 4; j++) acc[i][j] = (f32x4){0.f, 0.f, 0.f, 0.f};

    int ro = l & 15;              // fragment row/col within 16
    int koB = (l >> 4) * 16;      // k byte offset within 64B row
    const char* sm = (const char*)smem;

    for (int k0 = 0; k0 < DIM; k0 += 32) {
        // stage: wave w fills its 8KB tile (8 chunks x 1KB)
#pragma unroll
        for (int c = 0; c < 8; c++) {
            int r = rbase + c * 16 + (l >> 2);
            if (w < 2) r = min(r, M - 1);
            const ushort* src = sbase + (size_t)r * DIM + k0 + (l & 3) * 8;
            gload_lds16(src, ldst + c * 512);
        }
        __syncthreads();

        bf16x8 ah[4], al[4], bh[4], bl[4];
#pragma unroll
        for (int i = 0; i < 4; i++) {
            int arow = wm * 64 + i * 16 + ro;
            ah[i] = *(const bf16x8*)(sm + arow * 64 + koB);
            al[i] = *(const bf16x8*)(sm + 8192 + arow * 64 + koB);
            int brow = wn * 64 + i * 16 + ro;
            bh[i] = *(const bf16x8*)(sm + 16384 + brow * 64 + koB);
            bl[i] = *(const bf16x8*)(sm + 24576 + brow * 64 + koB);
        }
#pragma unroll
        for (int i = 0; i < 4; i++)
#pragma unroll
            for (int j = 0; j < 4; j++) {
                acc[i][j] = __builtin_amdgcn_mfma_f32_16x16x32_bf16(ah[i], bh[j], acc[i][j], 0, 0, 0);
                acc[i][j] = __builtin_amdgcn_mfma_f32_16x16x32_bf16(ah[i], bl[j], acc[i][j], 0, 0, 0);
                acc[i][j] = __builtin_amdgcn_mfma_f32_16x16x32_bf16(al[i], bh[j], acc[i][j], 0, 0, 0);
            }
        __syncthreads();
    }

    // epilogue: C/D layout col=lane&15, row=(lane>>4)*4+reg
    int colbase = bn + wn * 64 + ro;
    int rowbase = bm + wm * 64 + (l >> 4) * 4;
    float sacc[4] = {0.f, 0.f, 0.f, 0.f};
    float qacc[4] = {0.f, 0.f, 0.f, 0.f};
#pragma unroll
    for (int j = 0; j < 4; j++) {
        int col = colbase + j * 16;
        float bi = bias ? bias[col] : 0.f;
#pragma unroll
        for (int i = 0; i < 4; i++) {
#pragma unroll
            for (int r = 0; r < 4; r++) {
                int row = rowbase + i * 16 + r;
                if (row < M) {
                    float v = acc[i][j][r] + bi;
                    if (addmat) v += addmat[(size_t)row * DIM + col];
                    if (relu) v = fmaxf(v, 0.f);
                    if (mode == 0) {
                        Cf[(size_t)row * DIM + col] = v;
                    } else {
                        ushort h, lo;
                        split_bf(v, h, lo);
                        Oh[(size_t)row * DIM + col] = h;
                        Ol[(size_t)row * DIM + col] = lo;
                    }
                    if (stats) { sacc[j] += v; qacc[j] += v * v; }
                }
            }
        }
    }
    if (stats) {
#pragma unroll
        for (int j = 0; j < 4; j++) {
            float ss = sacc[j], qq = qacc[j];
            ss += __shfl_xor(ss, 16); qq += __shfl_xor(qq, 16);
            ss += __shfl_xor(ss, 32); qq += __shfl_xor(qq, 32);
            if ((l >> 4) == 0) {
                int col = colbase + j * 16;
                atomicAdd(&stats[col], ss);
                atomicAdd(&stats[DIM + col], qq);
            }
        }
    }
}

// ---------------- batch norm finalize / apply ----------------

__global__ void bn_finalize_kernel(float* st, const float* __restrict__ g,
                                   const float* __restrict__ b, int M) {
    int c = threadIdx.x;  // 512 threads
    float mean = st[c] / (float)M;
    float var = st[DIM + c] / (float)M - mean * mean;
    float sc = g[c] * rsqrtf(var + 1e-5f);
    st[1024 + c] = sc;
    st[1536 + c] = b[c] - mean * sc;
}

// mode 0: fp32 out (in-place ok). mode 1: bf16 pair out.
__global__ void bn_apply_kernel(const float* __restrict__ X, const float* __restrict__ st,
                                float* __restrict__ Yf, ushort* __restrict__ Yh,
                                ushort* __restrict__ Yl, int M, int relu, int mode) {
    const float* scale = st + 1024;
    const float* shift = st + 1536;
    size_t n4 = (size_t)M * DIM / 4;
    size_t i = (size_t)blockIdx.x * blockDim.x + threadIdx.x;
    size_t stride = (size_t)gridDim.x * blockDim.x;
    const float4* X4 = (const float4*)X;
    for (; i < n4; i += stride) {
        int col4 = (int)(i & (DIM / 4 - 1)) * 4;
        float4 v = X4[i];
        v.x = v.x * scale[col4 + 0] + shift[col4 + 0];
        v.y = v.y * scale[col4 + 1] + shift[col4 + 1];
        v.z = v.z * scale[col4 + 2] + shift[col4 + 2];
        v.w = v.w * scale[col4 + 3] + shift[col4 + 3];
        if (relu) {
            v.x = fmaxf(v.x, 0.f); v.y = fmaxf(v.y, 0.f);
            v.z = fmaxf(v.z, 0.f); v.w = fmaxf(v.w, 0.f);
        }
        if (mode == 0) {
            ((float4*)Yf)[i] = v;
        } else {
            size_t o = i * 4;
            ushort h, l;
            split_bf(v.x, h, l); Yh[o + 0] = h; Yl[o + 0] = l;
            split_bf(v.y, h, l); Yh[o + 1] = h; Yl[o + 1] = l;
            split_bf(v.z, h, l); Yh[o + 2] = h; Yl[o + 2] = l;
            split_bf(v.w, h, l); Yh[o + 3] = h; Yl[o + 3] = l;
        }
    }
}

// ---------------- final pair gather + (T,512)@(512,7) ----------------

__global__ __launch_bounds__(256) void pair_kernel(const float* __restrict__ H,
                                                   const int* __restrict__ ei,
                                                   const int* __restrict__ teid,
                                                   const float* __restrict__ W,  // 512x7
                                                   const float* __restrict__ bias,
                                                   float* __restrict__ out) {
    __shared__ float Wl[DIM * NCLS];
    for (int i = threadIdx.x; i < DIM * NCLS; i += 256) Wl[i] = W[i];
    __syncthreads();

    int wave = threadIdx.x >> 6;
    int lane = threadIdx.x & 63;
    int t = blockIdx.x * 4 + wave;
    if (t >= N_TRAIN) return;
    int id = teid[t];
    int n0 = ei[id];
    int n1 = ei[N_EDGES + id];
    const float4* a4 = (const float4*)(H + (size_t)n0 * DIM);
    const float4* b4 = (const float4*)(H + (size_t)n1 * DIM);
    float4 a0 = a4[lane * 2], a1 = a4[lane * 2 + 1];
    float4 b0 = b4[lane * 2], b1 = b4[lane * 2 + 1];
    float p[8] = {a0.x * b0.x, a0.y * b0.y, a0.z * b0.z, a0.w * b0.w,
                  a1.x * b1.x, a1.y * b1.y, a1.z * b1.z, a1.w * b1.w};
    int d0 = lane * 8;
    float acc[NCLS];
#pragma unroll
    for (int c = 0; c < NCLS; c++) acc[c] = 0.f;
#pragma unroll
    for (int q = 0; q < 8; q++) {
        const float* wrow = &Wl[(d0 + q) * NCLS];
#pragma unroll
        for (int c = 0; c < NCLS; c++) acc[c] += p[q] * wrow[c];
    }
#pragma unroll
    for (int off = 32; off; off >>= 1)
#pragma unroll
        for (int c = 0; c < NCLS; c++) acc[c] += __shfl_down(acc[c], off);
    if (lane == 0) {
#pragma unroll
        for (int c = 0; c < NCLS; c++) out[(size_t)t * NCLS + c] = acc[c] + bias[c];
    }
}

// ---------------- launch ----------------

extern "C" void kernel_launch(void* const* d_in, const int* in_sizes, int n_in,
                              void* d_out, int out_size, void* d_ws, size_t ws_size,
                              hipStream_t stream) {
    const float* x      = (const float*)d_in[0];
    const float* graph  = (const float*)d_in[1];
    const int*   ei     = (const int*)d_in[2];
    const int*   teid   = (const int*)d_in[3];
    const float* W_sub  = (const float*)d_in[4];
    const float* bn1_g  = (const float*)d_in[5];
    const float* bn1_b  = (const float*)d_in[6];
    const float* fcx_W  = (const float*)d_in[7];
    const float* fcx_b  = (const float*)d_in[8];
    const float* eps1   = (const float*)d_in[9];
    const float* g_W1   = (const float*)d_in[10];
    const float* g_b1   = (const float*)d_in[11];
    const float* g_W2   = (const float*)d_in[12];
    const float* g_b2   = (const float*)d_in[13];
    const float* gbn_g  = (const float*)d_in[14];
    const float* gbn_b  = (const float*)d_in[15];
    const float* lin1_W = (const float*)d_in[16];
    const float* lin1_b = (const float*)d_in[17];
    const float* lin2_W = (const float*)d_in[18];
    const float* lin2_b = (const float*)d_in[19];
    const float* fc2_W  = (const float*)d_in[20];
    const float* fc2_b  = (const float*)d_in[21];
    float* out = (float*)d_out;

    char* ws = (char*)d_ws;
    size_t NB = (size_t)N_NODES * DIM * sizeof(float);    // 102.4 MB per slot
    float* slotA = (float*)(ws);
    float* slotB = (float*)(ws + NB);
    float* slotC = (float*)(ws + 2 * NB);
    float* st1   = (float*)(ws + 3 * NB);                 // 2048 floats
    float* st2   = st1 + 2048;
    int* off     = (int*)(st2 + 2048);
    int* wcur    = off + (N_NODES + 1);
    int* srclist = wcur + N_NODES;
    int* bsum    = srclist + N_EDGES;
    ushort* wt   = (ushort*)(bsum + 256);                 // 6 W^T pairs, 1MB each
    ushort* Wsub_h = wt;                ushort* Wsub_l = wt + 262144;
    ushort* fcx_h  = wt + 2 * 262144;   ushort* fcx_l  = wt + 3 * 262144;
    ushort* gw1_h  = wt + 4 * 262144;   ushort* gw1_l  = wt + 5 * 262144;
    ushort* gw2_h  = wt + 6 * 262144;   ushort* gw2_l  = wt + 7 * 262144;
    ushort* lw1_h  = wt + 8 * 262144;   ushort* lw1_l  = wt + 9 * 262144;
    ushort* lw2_h  = wt + 10 * 262144;  ushort* lw2_l  = wt + 11 * 262144;

    // bf16-pair views of the fp32 slots (hi half then lo half)
    ushort* A_h = (ushort*)slotA; ushort* A_l = A_h + (size_t)N_NODES * DIM;
    ushort* C_h = (ushort*)slotC; ushort* C_l = C_h + (size_t)N_NODES * DIM;

    size_t n4 = (size_t)N_NODES * DIM / 4;
    dim3 ggrid((N_NODES + 127) / 128, DIM / 128);

    zero_kernel<<<16, 256, 0, stream>>>(st1, 4096);
    zero_kernel<<<NSB, 256, 0, stream>>>((float*)wcur, N_NODES);

    // CSR by dst
    hist_kernel<<<(N_EDGES + 255) / 256, 256, 0, stream>>>(ei, wcur);
    scan1_kernel<<<NSB, 256, 0, stream>>>(wcur, off, bsum);
    scan2_kernel<<<1, 256, 0, stream>>>(bsum);
    scan3_kernel<<<NSB, 256, 0, stream>>>(off, bsum);
    fillprep_kernel<<<NSB, 256, 0, stream>>>(off, wcur);
    fill_kernel<<<(N_EDGES + 255) / 256, 256, 0, stream>>>(ei, wcur, srclist);

    // W^T hi/lo conversions
    wconvert_kernel<<<1024, 256, 0, stream>>>(W_sub,  Wsub_h, Wsub_l);
    wconvert_kernel<<<1024, 256, 0, stream>>>(fcx_W,  fcx_h,  fcx_l);
    wconvert_kernel<<<1024, 256, 0, stream>>>(g_W1,   gw1_h,  gw1_l);
    wconvert_kernel<<<1024, 256, 0, stream>>>(g_W2,   gw2_h,  gw2_l);
    wconvert_kernel<<<1024, 256, 0, stream>>>(lin1_W, lw1_h,  lw1_l);
    wconvert_kernel<<<1024, 256, 0, stream>>>(lin2_W, lw2_h,  lw2_l);

    // agg_s = graph + gather(graph) -> pair in slotA
    gather_pair_kernel<<<N_NODES, 128, 0, stream>>>(graph, graph, nullptr, off, srclist, A_h, A_l);
    // GEMM1: slotB = agg_s @ W_sub + graph (fp32, stats st1)
    mfma_gemm_kernel<<<ggrid, 256, 0, stream>>>(A_h, A_l, Wsub_h, Wsub_l, nullptr, graph,
                                                slotB, nullptr, nullptr, st1, N_NODES, 0, 0);
    bn_finalize_kernel<<<1, 512, 0, stream>>>(st1, bn1_g, bn1_b, N_NODES);
    // sub_x = relu(BN(slotB)) fp32 in-place
    bn_apply_kernel<<<2048, 256, 0, stream>>>(slotB, st1, slotB, nullptr, nullptr, N_NODES, 1, 0);

    // x -> pair slotA ; GEMM2: h = x @ fcx_W + fcx_b (fp32 -> slotC)
    convert_pair_kernel<<<2048, 256, 0, stream>>>(x, A_h, A_l, n4);
    mfma_gemm_kernel<<<ggrid, 256, 0, stream>>>(A_h, A_l, fcx_h, fcx_l, fcx_b, nullptr,
                                                slotC, nullptr, nullptr, nullptr, N_NODES, 0, 0);

    // agg = (1+eps)*h + gather(h) -> pair slotA
    gather_pair_kernel<<<N_NODES, 128, 0, stream>>>(slotC, slotC, eps1, off, srclist, A_h, A_l);

    // GEMM3: relu(agg @ g_W1 + g_b1) -> pair slotC
    mfma_gemm_kernel<<<ggrid, 256, 0, stream>>>(A_h, A_l, gw1_h, gw1_l, g_b1, nullptr,
                                                nullptr, C_h, C_l, nullptr, N_NODES, 1, 1);
    // GEMM4: relu(h @ g_W2 + g_b2) -> fp32 slotA, stats st2
    mfma_gemm_kernel<<<ggrid, 256, 0, stream>>>(C_h, C_l, gw2_h, gw2_l, g_b2, nullptr,
                                                slotA, nullptr, nullptr, st2, N_NODES, 1, 0);
    bn_finalize_kernel<<<1, 512, 0, stream>>>(st2, gbn_g, gbn_b, N_NODES);
    // BN (no relu) -> pair slotC
    bn_apply_kernel<<<2048, 256, 0, stream>>>(slotA, st2, nullptr, C_h, C_l, N_NODES, 0, 1);

    // GEMM5: relu(h @ lin1_W + lin1_b) -> pair slotA
    mfma_gemm_kernel<<<ggrid, 256, 0, stream>>>(C_h, C_l, lw1_h, lw1_l, lin1_b, nullptr,
                                                nullptr, A_h, A_l, nullptr, N_NODES, 1, 1);
    // GEMM6: h = h @ lin2_W + lin2_b + sub_x -> fp32 slotC
    mfma_gemm_kernel<<<ggrid, 256, 0, stream>>>(A_h, A_l, lw2_h, lw2_l, lin2_b, slotB,
                                                slotC, nullptr, nullptr, nullptr, N_NODES, 0, 0);

    // out = (h[n0]*h[n1]) @ fc2_W + fc2_b
    pair_kernel<<<(N_TRAIN + 3) / 4, 256, 0, stream>>>(slotC, ei, teid, fc2_W, fc2_b, out);
}

// Round 4
// 1466.887 us; speedup vs baseline: 3.6009x; 1.1916x over previous
//
#include <hip/hip_runtime.h>

#define N_NODES 50000
#define N_EDGES 200000
#define N_TRAIN 100000
#define DIM     512
#define NCLS    7
#define NSB     ((N_NODES + 255) / 256)   // scan blocks = 196

typedef unsigned short ushort;
typedef __bf16 bf16x8 __attribute__((ext_vector_type(8)));
typedef float  f32x4  __attribute__((ext_vector_type(4)));

// ---------- bf16 helpers ----------
__device__ __forceinline__ ushort f2bf_rne(float f) {
    union { float f; unsigned u; } v; v.f = f;
    unsigned u = v.u;
    unsigned r = (u + 0x7fffu + ((u >> 16) & 1u)) >> 16;
    return (ushort)r;
}
__device__ __forceinline__ float bf2f(ushort h) {
    union { unsigned u; float f; } v; v.u = ((unsigned)h) << 16; return v.f;
}
__device__ __forceinline__ void split_bf(float f, ushort& h, ushort& l) {
    h = f2bf_rne(f);
    l = f2bf_rne(f - bf2f(h));
}

__device__ __forceinline__ void gload_lds16(const void* g, void* l) {
    __builtin_amdgcn_global_load_lds((const __attribute__((address_space(1))) unsigned int*)g,
                                     (__attribute__((address_space(3))) unsigned int*)l,
                                     16, 0, 0);
}

// ---------------- small utility kernels ----------------

__global__ void zero_kernel(float* p, int n) {
    int i = blockIdx.x * blockDim.x + threadIdx.x;
    if (i < n) p[i] = 0.0f;
}

// ---------------- CSR build (by dst) ----------------

__global__ void hist_kernel(const int* __restrict__ ei, int* __restrict__ cnt) {
    int e = blockIdx.x * blockDim.x + threadIdx.x;
    if (e < N_EDGES) atomicAdd(&cnt[ei[N_EDGES + e]], 1);
}

__global__ __launch_bounds__(256) void scan1_kernel(const int* __restrict__ cnt,
                                                    int* __restrict__ off,
                                                    int* __restrict__ bsum) {
    __shared__ int s[256];
    int t = threadIdx.x, b = blockIdx.x;
    int i = b * 256 + t;
    s[t] = (i < N_NODES) ? cnt[i] : 0;
    __syncthreads();
    for (int d = 1; d < 256; d <<= 1) {
        int add = (t >= d) ? s[t - d] : 0;
        __syncthreads();
        s[t] += add;
        __syncthreads();
    }
    if (i < N_NODES) off[i + 1] = s[t];
    if (t == 255) bsum[b] = s[255];
}

__global__ __launch_bounds__(256) void scan2_kernel(int* bsum) {
    __shared__ int s[256];
    int t = threadIdx.x;
    s[t] = (t < NSB) ? bsum[t] : 0;
    __syncthreads();
    for (int d = 1; d < 256; d <<= 1) {
        int add = (t >= d) ? s[t - d] : 0;
        __syncthreads();
        s[t] += add;
        __syncthreads();
    }
    if (t < NSB) bsum[t] = s[t];
}

__global__ __launch_bounds__(256) void scan3_kernel(int* off, const int* __restrict__ bsum) {
    int t = threadIdx.x, b = blockIdx.x;
    int i = b * 256 + t;
    if (i == 0) off[0] = 0;
    if (i < N_NODES) off[i + 1] += (b > 0 ? bsum[b - 1] : 0);
}

__global__ void fillprep_kernel(const int* __restrict__ off, int* __restrict__ wcur) {
    int i = blockIdx.x * blockDim.x + threadIdx.x;
    if (i < N_NODES) wcur[i] = off[i];
}

__global__ void fill_kernel(const int* __restrict__ ei, int* __restrict__ wcur,
                            int* __restrict__ srclist) {
    int e = blockIdx.x * blockDim.x + threadIdx.x;
    if (e < N_EDGES) {
        int d = ei[N_EDGES + e];
        int pos = atomicAdd(&wcur[d], 1);
        srclist[pos] = ei[e];
    }
}

// ---- aggregation: out[n] = scale*base[n] + sum feat[src], emitted as bf16 hi/lo pair ----

__global__ __launch_bounds__(128) void gather_pair_kernel(const float* __restrict__ feat,
                                                          const float* __restrict__ base,
                                                          const float* eps_or_null,
                                                          const int* __restrict__ off,
                                                          const int* __restrict__ srclist,
                                                          ushort* __restrict__ oh,
                                                          ushort* __restrict__ ol) {
    int n = blockIdx.x;
    int t = threadIdx.x;
    float s = 1.0f;
    if (eps_or_null) s = 1.0f + *eps_or_null;
    int e0 = off[n], e1 = off[n + 1];
    float4 acc = ((const float4*)(base + (size_t)n * DIM))[t];
    acc.x *= s; acc.y *= s; acc.z *= s; acc.w *= s;
    for (int e = e0; e < e1; ++e) {
        int srcn = srclist[e];
        float4 v = ((const float4*)(feat + (size_t)srcn * DIM))[t];
        acc.x += v.x; acc.y += v.y; acc.z += v.z; acc.w += v.w;
    }
    size_t o = (size_t)n * DIM + t * 4;
    ushort h, l;
    split_bf(acc.x, h, l); oh[o + 0] = h; ol[o + 0] = l;
    split_bf(acc.y, h, l); oh[o + 1] = h; ol[o + 1] = l;
    split_bf(acc.z, h, l); oh[o + 2] = h; ol[o + 2] = l;
    split_bf(acc.w, h, l); oh[o + 3] = h; ol[o + 3] = l;
}

// ---- fp32 -> bf16 pair (for x) ----
__global__ void convert_pair_kernel(const float* __restrict__ X,
                                    ushort* __restrict__ oh, ushort* __restrict__ ol,
                                    size_t n4) {
    size_t i = (size_t)blockIdx.x * blockDim.x + threadIdx.x;
    size_t stride = (size_t)gridDim.x * blockDim.x;
    const float4* X4 = (const float4*)X;
    for (; i < n4; i += stride) {
        float4 v = X4[i];
        size_t o = i * 4;
        ushort h, l;
        split_bf(v.x, h, l); oh[o + 0] = h; ol[o + 0] = l;
        split_bf(v.y, h, l); oh[o + 1] = h; ol[o + 1] = l;
        split_bf(v.z, h, l); oh[o + 2] = h; ol[o + 2] = l;
        split_bf(v.w, h, l); oh[o + 3] = h; ol[o + 3] = l;
    }
}

// ---- all 6 W (K x N fp32) -> transposed bf16 hi/lo [N][K], packed in wt ----
__global__ void wconvert6_kernel(const float* __restrict__ W0, const float* __restrict__ W1,
                                 const float* __restrict__ W2, const float* __restrict__ W3,
                                 const float* __restrict__ W4, const float* __restrict__ W5,
                                 ushort* __restrict__ wt) {
    int p = blockIdx.y;
    const float* W = (p == 0) ? W0 : (p == 1) ? W1 : (p == 2) ? W2
                   : (p == 3) ? W3 : (p == 4) ? W4 : W5;
    ushort* Th = wt + (size_t)p * 2 * 262144;
    ushort* Tl = Th + 262144;
    int idx = blockIdx.x * 256 + threadIdx.x;   // over 512*512
    int n = idx >> 9, k = idx & 511;
    float f = W[k * DIM + n];
    ushort h, l;
    split_bf(f, h, l);
    Th[idx] = h; Tl[idx] = l;
}

// ---------------- MFMA GEMM (2-phase dbuf + XCD swizzle + LDS XOR swizzle) ----------------
// C(MxDIM) = (Ah+Al) @ (Wh+Wl), W transposed [n][k]. 3 MFMA passes share the accumulator.
// Tile 128x128, BK=32, 4 waves (2x2), double-buffered 64KB LDS.
// LDS layout per tile: 128 rows x 64B; physical byte = logical_byte ^ (((row>>1)&3)<<4)
// applied on BOTH sides: staging pre-swizzles the global source k-chunk, reader swizzles
// its ds_read address (rule 21: same involution, row bits unchanged).

__global__ __launch_bounds__(256) void mfma_gemm_kernel(
    const ushort* __restrict__ Ah, const ushort* __restrict__ Al,
    const ushort* __restrict__ Bh, const ushort* __restrict__ Bl,   // W^T hi/lo [DIM][DIM]
    const float* __restrict__ bias,     // or null
    const float* __restrict__ addmat,   // or null
    const float* __restrict__ bnst,     // or null: with addmat -> addmat = relu(am*sc+sh)
    float* __restrict__ Cf,             // mode 0 out
    ushort* __restrict__ Oh, ushort* __restrict__ Ol,  // mode 1 out
    float* __restrict__ stats,          // or null: [0..511] sum, [512..1023] sumsq
    int M, int relu, int mode)
{
    __shared__ __align__(16) ushort smem[2 * 4 * 4096];   // 2 bufs x (Ah|Al|Bh|Bl) = 64KB

    int tid = threadIdx.x;
    int w = tid >> 6;       // wave 0..3
    int l = tid & 63;
    int wm = w >> 1, wn = w & 1;

    // bijective XCD chunk swizzle (m204), bn fastest -> column tiles of one row panel
    // land consecutively on the same XCD's L2.
    int nwg = gridDim.x;
    int q = nwg >> 3, r = nwg & 7;
    int xcd = blockIdx.x & 7, idx = blockIdx.x >> 3;
    int wgid = (xcd < r ? xcd * (q + 1) : r * (q + 1) + (xcd - r) * q) + idx;
    int bm = (wgid >> 2) * 128;
    int bn = (wgid & 3) * 128;

    // wave-uniform staging source select
    const ushort* sbase;
    int rbase; bool clampM;
    if (w == 0)      { sbase = Ah; rbase = bm; clampM = true; }
    else if (w == 1) { sbase = Al; rbase = bm; clampM = true; }
    else if (w == 2) { sbase = Bh; rbase = bn; clampM = false; }
    else             { sbase = Bl; rbase = bn; clampM = false; }

    f32x4 acc[4][4];
#pragma unroll
    for (int i = 0; i < 4; i++)
#pragma unroll
        for (int j = 0; j < 4; j++) acc[i][j] = (f32x4){0.f, 0.f, 0.f, 0.f};

    int ro = l & 15;              // fragment row/col within 16
    int co = l >> 4;              // 16B k-chunk 0..3

    // prologue: stage k0=0 into buf0
    {
        ushort* ldst = smem + w * 4096;
#pragma unroll
        for (int c = 0; c < 8; c++) {
            int rit = c * 16 + (l >> 2);
            int rr = rbase + rit;
            if (clampM) rr = min(rr, M - 1);
            int kc = (l & 3) ^ ((rit >> 1) & 3);   // pre-swizzled source chunk
            gload_lds16(sbase + (size_t)rr * DIM + kc * 8, ldst + c * 512);
        }
    }
    __syncthreads();

    int cur = 0;
    for (int ks = 0; ks < 16; ks++) {
        // stage next k-slice into the other buffer; flight time hides under MFMA
        if (ks < 15) {
            int k0n = (ks + 1) * 32;
            ushort* ldst = smem + (cur ^ 1) * 16384 + w * 4096;
#pragma unroll
            for (int c = 0; c < 8; c++) {
                int rit = c * 16 + (l >> 2);
                int rr = rbase + rit;
                if (clampM) rr = min(rr, M - 1);
                int kc = (l & 3) ^ ((rit >> 1) & 3);
                gload_lds16(sbase + (size_t)rr * DIM + k0n + kc * 8, ldst + c * 512);
            }
        }

        const char* bb = (const char*)smem + cur * 32768;
        bf16x8 ah[4], al[4], bh[4], bl[4];
#pragma unroll
        for (int i = 0; i < 4; i++) {
            int arow = wm * 64 + i * 16 + ro;
            int sa = (co ^ ((arow >> 1) & 3)) << 4;
            ah[i] = *(const bf16x8*)(bb + arow * 64 + sa);
            al[i] = *(const bf16x8*)(bb + 8192 + arow * 64 + sa);
            int brow = wn * 64 + i * 16 + ro;
            int sb = (co ^ ((brow >> 1) & 3)) << 4;
            bh[i] = *(const bf16x8*)(bb + 16384 + brow * 64 + sb);
            bl[i] = *(const bf16x8*)(bb + 24576 + brow * 64 + sb);
        }
#pragma unroll
        for (int i = 0; i < 4; i++)
#pragma unroll
            for (int j = 0; j < 4; j++) {
                acc[i][j] = __builtin_amdgcn_mfma_f32_16x16x32_bf16(ah[i], bh[j], acc[i][j], 0, 0, 0);
                acc[i][j] = __builtin_amdgcn_mfma_f32_16x16x32_bf16(ah[i], bl[j], acc[i][j], 0, 0, 0);
                acc[i][j] = __builtin_amdgcn_mfma_f32_16x16x32_bf16(al[i], bh[j], acc[i][j], 0, 0, 0);
            }
        __syncthreads();   // drains lgkm + vmcnt(0): next buffer ready, reads done
        cur ^= 1;
    }

    // epilogue: C/D layout col=lane&15, row=(lane>>4)*4+reg
    int colbase = bn + wn * 64 + ro;
    int rowbase = bm + wm * 64 + co * 4;
    float sacc[4] = {0.f, 0.f, 0.f, 0.f};
    float qacc[4] = {0.f, 0.f, 0.f, 0.f};
#pragma unroll
    for (int j = 0; j < 4; j++) {
        int col = colbase + j * 16;
        float bi = bias ? bias[col] : 0.f;
        float sc = 0.f, sh = 0.f;
        if (bnst) { sc = bnst[1024 + col]; sh = bnst[1536 + col]; }
#pragma unroll
        for (int i = 0; i < 4; i++) {
#pragma unroll
            for (int rg = 0; rg < 4; rg++) {
                int row = rowbase + i * 16 + rg;
                if (row < M) {
                    float v = acc[i][j][rg] + bi;
                    if (addmat) {
                        float am = addmat[(size_t)row * DIM + col];
                        if (bnst) am = fmaxf(am * sc + sh, 0.f);
                        v += am;
                    }
                    if (relu) v = fmaxf(v, 0.f);
                    if (mode == 0) {
                        Cf[(size_t)row * DIM + col] = v;
                    } else {
                        ushort h, lo;
                        split_bf(v, h, lo);
                        Oh[(size_t)row * DIM + col] = h;
                        Ol[(size_t)row * DIM + col] = lo;
                    }
                    if (stats) { sacc[j] += v; qacc[j] += v * v; }
                }
            }
        }
    }
    if (stats) {
#pragma unroll
        for (int j = 0; j < 4; j++) {
            float ss = sacc[j], qq = qacc[j];
            ss += __shfl_xor(ss, 16); qq += __shfl_xor(qq, 16);
            ss += __shfl_xor(ss, 32); qq += __shfl_xor(qq, 32);
            if ((l >> 4) == 0) {
                int col = colbase + j * 16;
                atomicAdd(&stats[col], ss);
                atomicAdd(&stats[DIM + col], qq);
            }
        }
    }
}

// ---------------- batch norm finalize / apply ----------------

__global__ void bn_finalize_kernel(float* st, const float* __restrict__ g,
                                   const float* __restrict__ b, int M) {
    int c = threadIdx.x;  // 512 threads
    float mean = st[c] / (float)M;
    float var = st[DIM + c] / (float)M - mean * mean;
    float sc = g[c] * rsqrtf(var + 1e-5f);
    st[1024 + c] = sc;
    st[1536 + c] = b[c] - mean * sc;
}

// mode 0: fp32 out. mode 1: bf16 pair out.
__global__ void bn_apply_kernel(const float* __restrict__ X, const float* __restrict__ st,
                                float* __restrict__ Yf, ushort* __restrict__ Yh,
                                ushort* __restrict__ Yl, int M, int relu, int mode) {
    const float* scale = st + 1024;
    const float* shift = st + 1536;
    size_t n4 = (size_t)M * DIM / 4;
    size_t i = (size_t)blockIdx.x * blockDim.x + threadIdx.x;
    size_t stride = (size_t)gridDim.x * blockDim.x;
    const float4* X4 = (const float4*)X;
    for (; i < n4; i += stride) {
        int col4 = (int)(i & (DIM / 4 - 1)) * 4;
        float4 v = X4[i];
        v.x = v.x * scale[col4 + 0] + shift[col4 + 0];
        v.y = v.y * scale[col4 + 1] + shift[col4 + 1];
        v.z = v.z * scale[col4 + 2] + shift[col4 + 2];
        v.w = v.w * scale[col4 + 3] + shift[col4 + 3];
        if (relu) {
            v.x = fmaxf(v.x, 0.f); v.y = fmaxf(v.y, 0.f);
            v.z = fmaxf(v.z, 0.f); v.w = fmaxf(v.w, 0.f);
        }
        if (mode == 0) {
            ((float4*)Yf)[i] = v;
        } else {
            size_t o = i * 4;
            ushort h, l;
            split_bf(v.x, h, l); Yh[o + 0] = h; Yl[o + 0] = l;
            split_bf(v.y, h, l); Yh[o + 1] = h; Yl[o + 1] = l;
            split_bf(v.z, h, l); Yh[o + 2] = h; Yl[o + 2] = l;
            split_bf(v.w, h, l); Yh[o + 3] = h; Yl[o + 3] = l;
        }
    }
}

// ---------------- final pair gather + (T,512)@(512,7) ----------------

__global__ __launch_bounds__(256) void pair_kernel(const float* __restrict__ H,
                                                   const int* __restrict__ ei,
                                                   const int* __restrict__ teid,
                                                   const float* __restrict__ W,  // 512x7
                                                   const float* __restrict__ bias,
                                                   float* __restrict__ out) {
    __shared__ float Wl[DIM * NCLS];
    for (int i = threadIdx.x; i < DIM * NCLS; i += 256) Wl[i] = W[i];
    __syncthreads();

    int wave = threadIdx.x >> 6;
    int lane = threadIdx.x & 63;
    int t = blockIdx.x * 4 + wave;
    if (t >= N_TRAIN) return;
    int id = teid[t];
    int n0 = ei[id];
    int n1 = ei[N_EDGES + id];
    const float4* a4 = (const float4*)(H + (size_t)n0 * DIM);
    const float4* b4 = (const float4*)(H + (size_t)n1 * DIM);
    float4 a0 = a4[lane * 2], a1 = a4[lane * 2 + 1];
    float4 b0 = b4[lane * 2], b1 = b4[lane * 2 + 1];
    float p[8] = {a0.x * b0.x, a0.y * b0.y, a0.z * b0.z, a0.w * b0.w,
                  a1.x * b1.x, a1.y * b1.y, a1.z * b1.z, a1.w * b1.w};
    int d0 = lane * 8;
    float acc[NCLS];
#pragma unroll
    for (int c = 0; c < NCLS; c++) acc[c] = 0.f;
#pragma unroll
    for (int qd = 0; qd < 8; qd++) {
        const float* wrow = &Wl[(d0 + qd) * NCLS];
#pragma unroll
        for (int c = 0; c < NCLS; c++) acc[c] += p[qd] * wrow[c];
    }
#pragma unroll
    for (int off = 32; off; off >>= 1)
#pragma unroll
        for (int c = 0; c < NCLS; c++) acc[c] += __shfl_down(acc[c], off);
    if (lane == 0) {
#pragma unroll
        for (int c = 0; c < NCLS; c++) out[(size_t)t * NCLS + c] = acc[c] + bias[c];
    }
}

// ---------------- launch ----------------

extern "C" void kernel_launch(void* const* d_in, const int* in_sizes, int n_in,
                              void* d_out, int out_size, void* d_ws, size_t ws_size,
                              hipStream_t stream) {
    const float* x      = (const float*)d_in[0];
    const float* graph  = (const float*)d_in[1];
    const int*   ei     = (const int*)d_in[2];
    const int*   teid   = (const int*)d_in[3];
    const float* W_sub  = (const float*)d_in[4];
    const float* bn1_g  = (const float*)d_in[5];
    const float* bn1_b  = (const float*)d_in[6];
    const float* fcx_W  = (const float*)d_in[7];
    const float* fcx_b  = (const float*)d_in[8];
    const float* eps1   = (const float*)d_in[9];
    const float* g_W1   = (const float*)d_in[10];
    const float* g_b1   = (const float*)d_in[11];
    const float* g_W2   = (const float*)d_in[12];
    const float* g_b2   = (const float*)d_in[13];
    const float* gbn_g  = (const float*)d_in[14];
    const float* gbn_b  = (const float*)d_in[15];
    const float* lin1_W = (const float*)d_in[16];
    const float* lin1_b = (const float*)d_in[17];
    const float* lin2_W = (const float*)d_in[18];
    const float* lin2_b = (const float*)d_in[19];
    const float* fc2_W  = (const float*)d_in[20];
    const float* fc2_b  = (const float*)d_in[21];
    float* out = (float*)d_out;

    char* ws = (char*)d_ws;
    size_t NB = (size_t)N_NODES * DIM * sizeof(float);    // 102.4 MB per slot
    float* slotA = (float*)(ws);
    float* slotB = (float*)(ws + NB);
    float* slotC = (float*)(ws + 2 * NB);
    float* st1   = (float*)(ws + 3 * NB);                 // 2048 floats
    float* st2   = st1 + 2048;
    int* off     = (int*)(st2 + 2048);
    int* wcur    = off + (N_NODES + 1);
    int* srclist = wcur + N_NODES;
    int* bsum    = srclist + N_EDGES;
    ushort* wt   = (ushort*)(bsum + 256);                 // 6 W^T pairs, 1MB each
    ushort* Wsub_h = wt;                ushort* Wsub_l = wt + 262144;
    ushort* fcx_h  = wt + 2 * 262144;   ushort* fcx_l  = wt + 3 * 262144;
    ushort* gw1_h  = wt + 4 * 262144;   ushort* gw1_l  = wt + 5 * 262144;
    ushort* gw2_h  = wt + 6 * 262144;   ushort* gw2_l  = wt + 7 * 262144;
    ushort* lw1_h  = wt + 8 * 262144;   ushort* lw1_l  = wt + 9 * 262144;
    ushort* lw2_h  = wt + 10 * 262144;  ushort* lw2_l  = wt + 11 * 262144;

    // bf16-pair views of the fp32 slots (hi half then lo half)
    ushort* A_h = (ushort*)slotA; ushort* A_l = A_h + (size_t)N_NODES * DIM;
    ushort* C_h = (ushort*)slotC; ushort* C_l = C_h + (size_t)N_NODES * DIM;

    size_t n4 = (size_t)N_NODES * DIM / 4;
    int mt = (N_NODES + 127) / 128;           // 391
    dim3 ggrid(mt * 4);                        // 1-D, bn fastest inside kernel

    zero_kernel<<<16, 256, 0, stream>>>(st1, 4096);
    zero_kernel<<<NSB, 256, 0, stream>>>((float*)wcur, N_NODES);

    // CSR by dst
    hist_kernel<<<(N_EDGES + 255) / 256, 256, 0, stream>>>(ei, wcur);
    scan1_kernel<<<NSB, 256, 0, stream>>>(wcur, off, bsum);
    scan2_kernel<<<1, 256, 0, stream>>>(bsum);
    scan3_kernel<<<NSB, 256, 0, stream>>>(off, bsum);
    fillprep_kernel<<<NSB, 256, 0, stream>>>(off, wcur);
    fill_kernel<<<(N_EDGES + 255) / 256, 256, 0, stream>>>(ei, wcur, srclist);

    // all W^T hi/lo conversions in one launch
    wconvert6_kernel<<<dim3(1024, 6), 256, 0, stream>>>(W_sub, fcx_W, g_W1, g_W2, lin1_W, lin2_W, wt);

    // agg_s = graph + gather(graph) -> pair in slotA
    gather_pair_kernel<<<N_NODES, 128, 0, stream>>>(graph, graph, nullptr, off, srclist, A_h, A_l);
    // GEMM1: slotB = agg_s @ W_sub + graph (fp32 raw, stats st1). BN applied lazily in GEMM6.
    mfma_gemm_kernel<<<ggrid, 256, 0, stream>>>(A_h, A_l, Wsub_h, Wsub_l, nullptr, graph, nullptr,
                                                slotB, nullptr, nullptr, st1, N_NODES, 0, 0);
    bn_finalize_kernel<<<1, 512, 0, stream>>>(st1, bn1_g, bn1_b, N_NODES);

    // x -> pair slotA ; GEMM2: h = x @ fcx_W + fcx_b (fp32 -> slotC)
    convert_pair_kernel<<<2048, 256, 0, stream>>>(x, A_h, A_l, n4);
    mfma_gemm_kernel<<<ggrid, 256, 0, stream>>>(A_h, A_l, fcx_h, fcx_l, fcx_b, nullptr, nullptr,
                                                slotC, nullptr, nullptr, nullptr, N_NODES, 0, 0);

    // agg = (1+eps)*h + gather(h) -> pair slotA
    gather_pair_kernel<<<N_NODES, 128, 0, stream>>>(slotC, slotC, eps1, off, srclist, A_h, A_l);

    // GEMM3: relu(agg @ g_W1 + g_b1) -> pair slotC
    mfma_gemm_kernel<<<ggrid, 256, 0, stream>>>(A_h, A_l, gw1_h, gw1_l, g_b1, nullptr, nullptr,
                                                nullptr, C_h, C_l, nullptr, N_NODES, 1, 1);
    // GEMM4: relu(h @ g_W2 + g_b2) -> fp32 slotA, stats st2
    mfma_gemm_kernel<<<ggrid, 256, 0, stream>>>(C_h, C_l, gw2_h, gw2_l, g_b2, nullptr, nullptr,
                                                slotA, nullptr, nullptr, st2, N_NODES, 1, 0);
    bn_finalize_kernel<<<1, 512, 0, stream>>>(st2, gbn_g, gbn_b, N_NODES);
    // BN (no relu) -> pair slotC
    bn_apply_kernel<<<2048, 256, 0, stream>>>(slotA, st2, nullptr, C_h, C_l, N_NODES, 0, 1);

    // GEMM5: relu(h @ lin1_W + lin1_b) -> pair slotA
    mfma_gemm_kernel<<<ggrid, 256, 0, stream>>>(C_h, C_l, lw1_h, lw1_l, lin1_b, nullptr, nullptr,
                                                nullptr, A_h, A_l, nullptr, N_NODES, 1, 1);
    // GEMM6: h = h @ lin2_W + lin2_b + relu(bn(slotB)) -> fp32 slotC (BN1 fused via st1)
    mfma_gemm_kernel<<<ggrid, 256, 0, stream>>>(A_h, A_l, lw2_h, lw2_l, lin2_b, slotB, st1,
                                                slotC, nullptr, nullptr, nullptr, N_NODES, 0, 0);

    // out = (h[n0]*h[n1]) @ fc2_W + fc2_b
    pair_kernel<<<(N_TRAIN + 3) / 4, 256, 0, stream>>>(slotC, ei, teid, fc2_W, fc2_b, out);
}